// Round 3
// baseline (303.389 us; speedup 1.0000x reference)
//
#include <hip/hip_runtime.h>

#define BB 16
#define SS 2048
#define HH 512
#define ON 16
#define INV_SQRT_H 0.04419417382415922f

// ---- ws float offsets. [0, ZERO_N) is atomically accumulated -> one memset.
#define WKO_OFF 0                  // [16][512]   8192
#define C_OFF   8192               // [16]
#define L_OFF   8208               // [B*O]       256
#define TT_OFF  8464               // [B*O]       256
#define G_OFF   8720               // [B][O][K]   131072
#define OO_OFF  139792             // [B][O][H]   131072
#define ZERO_N  270864
#define OQT_OFF 270864             // [H][O]      8192
#define LG_OFF  279056             // [B*S][O]    524288
#define WVT_OFF 803344             // [K][H]      262144  (end 1065488 floats)

// ---------------- K1: oq[o,h] = sum_s ops[s,o]*Wq[h,s] + bq[h]
__global__ __launch_bounds__(256) void k_oq(const float* __restrict__ Wq,
                                            const float* __restrict__ bq,
                                            const float* __restrict__ ops,
                                            float* __restrict__ ws,
                                            float* __restrict__ oq_out) {
  const int h = blockIdx.x;
  const int t = threadIdx.x;
  float4 acc[4];
  #pragma unroll
  for (int m = 0; m < 4; ++m) acc[m] = make_float4(0.f, 0.f, 0.f, 0.f);
  for (int s = t; s < SS; s += 256) {
    float wq = Wq[(size_t)h * SS + s];
    const float4* op4 = reinterpret_cast<const float4*>(ops + (size_t)s * ON);
    #pragma unroll
    for (int m = 0; m < 4; ++m) {
      float4 v = op4[m];
      acc[m].x += wq * v.x; acc[m].y += wq * v.y;
      acc[m].z += wq * v.z; acc[m].w += wq * v.w;
    }
  }
  __shared__ float red[256][ON];
  #pragma unroll
  for (int m = 0; m < 4; ++m) {
    red[t][4*m+0] = acc[m].x; red[t][4*m+1] = acc[m].y;
    red[t][4*m+2] = acc[m].z; red[t][4*m+3] = acc[m].w;
  }
  __syncthreads();
  for (int st = 128; st > 0; st >>= 1) {
    if (t < st) {
      #pragma unroll
      for (int o = 0; o < ON; ++o) red[t][o] += red[t + st][o];
    }
    __syncthreads();
  }
  if (t < ON) {
    float v = red[0][t] + bq[h];
    oq_out[(size_t)t * HH + h] = v;          // output 1: operator_queries [O,H]
    ws[OQT_OFF + (size_t)h * ON + t] = v;    // oqT[h][o]
  }
}

// ---------------- K2: Wko[o,k] = sum_h oq[o,h]*Wk[h,k]; c[o] = sum_h bk[h]*oq[o,h]
__global__ __launch_bounds__(256) void k_wko(const float* __restrict__ Wk,
                                             const float* __restrict__ bk,
                                             float* __restrict__ ws) {
  const int o = blockIdx.x;   // 16
  const int hc = blockIdx.y;  // 8 chunks of 64 h
  const int t = threadIdx.x;
  const float* __restrict__ oqT = ws + OQT_OFF;
  const int h0 = hc * 64;
  float acc0 = 0.f, acc1 = 0.f;
  for (int h = h0; h < h0 + 64; ++h) {
    float q = oqT[(size_t)h * ON + o];
    acc0 += q * Wk[(size_t)h * HH + t];
    acc1 += q * Wk[(size_t)h * HH + t + 256];
  }
  unsafeAtomicAdd(&ws[WKO_OFF + (size_t)o * HH + t], acc0);
  unsafeAtomicAdd(&ws[WKO_OFF + (size_t)o * HH + t + 256], acc1);
  if (t == 0) {
    float cp = 0.f;
    for (int h = h0; h < h0 + 64; ++h) cp += bk[h] * oqT[(size_t)h * ON + o];
    unsafeAtomicAdd(&ws[C_OFF + o], cp);
  }
}

// ---------------- K3pre: WvT[k][h] = Wv[h][k]
__global__ __launch_bounds__(256) void k_wvt(const float* __restrict__ Wv,
                                             float* __restrict__ ws) {
  __shared__ float tile[32][33];
  const int tx = threadIdx.x, ty = threadIdx.y;
  const int x0 = blockIdx.x * 32, y0 = blockIdx.y * 32;
  #pragma unroll
  for (int j = 0; j < 4; ++j)
    tile[ty + 8 * j][tx] = Wv[(size_t)(y0 + ty + 8 * j) * HH + x0 + tx];
  __syncthreads();
  float* WvT = ws + WVT_OFF;
  #pragma unroll
  for (int j = 0; j < 4; ++j)
    WvT[(size_t)(x0 + ty + 8 * j) * HH + y0 + tx] = tile[tx][ty + 8 * j];
}

// ---------------- K4 (fused): logits + L/t~ partials + G~ accumulation.
// grid (16 b, 128 sc); block 256 = 4 waves. 16 rows per block -> 2048 blocks,
// 8 blocks/CU: latency hidden by TLP instead of LDS staging.
__global__ __launch_bounds__(256) void k_main(const float* __restrict__ x,
                                              const float* __restrict__ ops,
                                              float* __restrict__ ws) {
  const int b = blockIdx.x, sc = blockIdx.y, t = threadIdx.x;
  const int sbase = sc * 16;
  const size_t xbase = ((size_t)b * SS + sbase) * HH;

  __shared__ float red[4][16][17];   // per-wave k-quarter partials
  __shared__ float el[16][16];       // exp(logit)           (for L)
  __shared__ float elo[16][16];      // exp(logit)*ops[s,o]  (for t~ and G~)

  // ---- phase A: logits. wave = k-quarter; lane -> (row, o-quad).
  const int kq = t >> 6, lane = t & 63;
  const int rg = lane >> 2, oq = lane & 3;
  const int k0 = kq * 128;

  float acc[4] = {0.f, 0.f, 0.f, 0.f};
  const float4* __restrict__ wko4 = reinterpret_cast<const float4*>(ws + WKO_OFF);
  const float* __restrict__ xrow = x + xbase + (size_t)rg * HH;
  #pragma unroll 8
  for (int ch = 0; ch < 32; ++ch) {
    const int kk = k0 + ch * 4;
    float4 xv = *reinterpret_cast<const float4*>(xrow + kk);
    #pragma unroll
    for (int j = 0; j < 4; ++j) {
      float4 w = wko4[(4 * oq + j) * 128 + (kk >> 2)];
      acc[j] += xv.x * w.x + xv.y * w.y + xv.z * w.z + xv.w * w.w;
    }
  }
  #pragma unroll
  for (int j = 0; j < 4; ++j) red[kq][rg][4 * oq + j] = acc[j];
  __syncthreads();

  // ---- finalize logits: thread -> (row = t>>4, o = t&15)
  {
    const int r = t >> 4, o = t & 15;
    float s = red[0][r][o] + red[1][r][o] + red[2][r][o] + red[3][r][o]
            + ws[C_OFF + o];
    float lg = s * INV_SQRT_H;
    ws[LG_OFF + ((size_t)b * SS + sbase + r) * ON + o] = lg;
    // exp without max-subtract: |logit| <~ 2 for this data, fp32-safe
    float e = __expf(lg);
    el[r][o] = e;
    elo[r][o] = e * ops[(size_t)(sbase + r) * ON + o];   // << ops factor (R2 bug fix)
  }
  __syncthreads();

  // ---- L and t~ partials
  if (t < ON) {
    float sl = 0.f, st = 0.f;
    #pragma unroll
    for (int r = 0; r < 16; ++r) { sl += el[r][t]; st += elo[r][t]; }
    unsafeAtomicAdd(&ws[L_OFF + b * ON + t], sl);
    unsafeAtomicAdd(&ws[TT_OFF + b * ON + t], st);
  }

  // ---- phase B: G~[b,o,k] += sum_s elo[s][o] * x[s][k].  lane = k; x is cache-hot.
  float a0[ON], a1[ON];
  #pragma unroll
  for (int o = 0; o < ON; ++o) { a0[o] = 0.f; a1[o] = 0.f; }
  const float4* elo4 = reinterpret_cast<const float4*>(&elo[0][0]);
  for (int s = 0; s < 16; ++s) {
    const float xv0 = x[xbase + (size_t)s * HH + t];
    const float xv1 = x[xbase + (size_t)s * HH + t + 256];
    #pragma unroll
    for (int g = 0; g < 4; ++g) {
      float4 e = elo4[s * 4 + g];
      a0[4*g+0] += e.x * xv0; a1[4*g+0] += e.x * xv1;
      a0[4*g+1] += e.y * xv0; a1[4*g+1] += e.y * xv1;
      a0[4*g+2] += e.z * xv0; a1[4*g+2] += e.z * xv1;
      a0[4*g+3] += e.w * xv0; a1[4*g+3] += e.w * xv1;
    }
  }
  float* G = ws + G_OFF + (size_t)b * ON * HH;
  #pragma unroll
  for (int o = 0; o < ON; ++o) {
    unsafeAtomicAdd(&G[(size_t)o * HH + t], a0[o]);
    unsafeAtomicAdd(&G[(size_t)o * HH + t + 256], a1[o]);
  }
}

// ---------------- K5: OO[b,o,h] = (sum_k G~*WvT)/L + bv*t~/L. grid (16,4,4): k-split.
__global__ __launch_bounds__(256) void k_oo(const float* __restrict__ bv,
                                            float* __restrict__ ws) {
  const int b = blockIdx.x, oqi = blockIdx.y, kq = blockIdx.z, t = threadIdx.x;
  const int o0 = oqi * 4, k0 = kq * 128;
  __shared__ float Gs[4][128];
  __shared__ float invLs[4], tts[4];
  if (t < 4) {
    float invL = 1.f / ws[L_OFF + b * ON + o0 + t];
    invLs[t] = invL;
    tts[t] = ws[TT_OFF + b * ON + o0 + t] * invL;
  }
  __syncthreads();
  {
    int idx = t;
    #pragma unroll
    for (int p = 0; p < 2; ++p, idx += 256) {
      int oo = idx >> 7, kk = idx & 127;
      Gs[oo][kk] = ws[G_OFF + ((size_t)b * ON + o0 + oo) * HH + k0 + kk] * invLs[oo];
    }
  }
  __syncthreads();
  const float* __restrict__ WvT = ws + WVT_OFF;
  float acc[4][2];
  #pragma unroll
  for (int o = 0; o < 4; ++o) { acc[o][0] = 0.f; acc[o][1] = 0.f; }
  for (int k = 0; k < 128; ++k) {
    const float w0 = WvT[(size_t)(k0 + k) * HH + t];
    const float w1 = WvT[(size_t)(k0 + k) * HH + t + 256];
    #pragma unroll
    for (int o = 0; o < 4; ++o) {
      const float g = Gs[o][k];
      acc[o][0] += g * w0; acc[o][1] += g * w1;
    }
  }
  float* OOp = ws + OO_OFF + ((size_t)b * ON + o0) * HH;
  #pragma unroll
  for (int o = 0; o < 4; ++o) {
    float add0 = acc[o][0], add1 = acc[o][1];
    if (kq == 0) { add0 += bv[t] * tts[o]; add1 += bv[t + 256] * tts[o]; }
    unsafeAtomicAdd(&OOp[(size_t)o * HH + t], add0);
    unsafeAtomicAdd(&OOp[(size_t)o * HH + t + 256], add1);
  }
}

// ---------------- K6: out[row,h] = sum_o softmax_o(lg[row,:])[o] * OO[b,o,h]
__global__ __launch_bounds__(256) void k_out(float* __restrict__ ws,
                                             float* __restrict__ out) {
  const int b = blockIdx.x, sc = blockIdx.y, t = threadIdx.x;
  const int rbase = b * SS + sc * 128;
  __shared__ float OOs[ON * HH];     // 32 KB
  __shared__ float wl[128 * ON];     // 8 KB
  const float4* OO4 = reinterpret_cast<const float4*>(ws + OO_OFF + (size_t)(b * ON) * HH);
  float4* OOs4 = reinterpret_cast<float4*>(OOs);
  #pragma unroll
  for (int j = 0; j < 8; ++j) OOs4[t + 256 * j] = OO4[t + 256 * j];
  if (t < 128) {
    const float4* lg4 = reinterpret_cast<const float4*>(ws + LG_OFF + (size_t)(rbase + t) * ON);
    float l[ON];
    float4 p0 = lg4[0], p1 = lg4[1], p2 = lg4[2], p3 = lg4[3];
    l[0]=p0.x; l[1]=p0.y; l[2]=p0.z; l[3]=p0.w;
    l[4]=p1.x; l[5]=p1.y; l[6]=p1.z; l[7]=p1.w;
    l[8]=p2.x; l[9]=p2.y; l[10]=p2.z; l[11]=p2.w;
    l[12]=p3.x; l[13]=p3.y; l[14]=p3.z; l[15]=p3.w;
    float m = l[0];
    #pragma unroll
    for (int o = 1; o < ON; ++o) m = fmaxf(m, l[o]);
    float sum = 0.f;
    #pragma unroll
    for (int o = 0; o < ON; ++o) { l[o] = __expf(l[o] - m); sum += l[o]; }
    float inv = 1.f / sum;
    #pragma unroll
    for (int o = 0; o < ON; ++o) wl[t * ON + o] = l[o] * inv;
  }
  __syncthreads();
  const int rsub = t >> 7, hq = t & 127;
  float oo[ON][4];
  #pragma unroll
  for (int o = 0; o < ON; ++o)
    #pragma unroll
    for (int j = 0; j < 4; ++j) oo[o][j] = OOs[o * HH + hq + 128 * j];
  const float4* wl4 = reinterpret_cast<const float4*>(wl);
  for (int i = 0; i < 64; ++i) {
    const int r = rsub * 64 + i;
    float4 w0 = wl4[r * 4 + 0], w1 = wl4[r * 4 + 1], w2 = wl4[r * 4 + 2], w3 = wl4[r * 4 + 3];
    float w[ON];
    w[0]=w0.x; w[1]=w0.y; w[2]=w0.z; w[3]=w0.w;
    w[4]=w1.x; w[5]=w1.y; w[6]=w1.z; w[7]=w1.w;
    w[8]=w2.x; w[9]=w2.y; w[10]=w2.z; w[11]=w2.w;
    w[12]=w3.x; w[13]=w3.y; w[14]=w3.z; w[15]=w3.w;
    float* orow = out + (size_t)(rbase + r) * HH + hq;
    #pragma unroll
    for (int j = 0; j < 4; ++j) {
      float v = 0.f;
      #pragma unroll
      for (int o = 0; o < ON; ++o) v += w[o] * oo[o][j];
      orow[128 * j] = v;
    }
  }
}

extern "C" void kernel_launch(void* const* d_in, const int* in_sizes, int n_in,
                              void* d_out, int out_size, void* d_ws, size_t ws_size,
                              hipStream_t stream) {
  const float* x   = (const float*)d_in[0];
  const float* Wv  = (const float*)d_in[1];
  const float* bv  = (const float*)d_in[2];
  const float* Wk  = (const float*)d_in[3];
  const float* bk  = (const float*)d_in[4];
  const float* Wq  = (const float*)d_in[5];
  const float* bq  = (const float*)d_in[6];
  const float* ops = (const float*)d_in[7];
  float* out = (float*)d_out;
  float* ws  = (float*)d_ws;
  float* oq_out = out + (size_t)BB * SS * HH;

  // single contiguous memset for all atomic accumulators
  hipMemsetAsync(ws, 0, (size_t)ZERO_N * sizeof(float), stream);

  k_wvt<<<dim3(16, 16), dim3(32, 8), 0, stream>>>(Wv, ws);
  k_oq<<<512, 256, 0, stream>>>(Wq, bq, ops, ws, oq_out);
  k_wko<<<dim3(16, 8), 256, 0, stream>>>(Wk, bk, ws);
  k_main<<<dim3(16, 128), 256, 0, stream>>>(x, ops, ws);
  k_oo<<<dim3(16, 4, 4), 256, 0, stream>>>(bv, ws);
  k_out<<<dim3(16, 16), 256, 0, stream>>>(ws, out);
}

// Round 4
// 223.273 us; speedup vs baseline: 1.3588x; 1.3588x over previous
//
#include <hip/hip_runtime.h>

#define BB 16
#define SS 2048
#define HH 512
#define ON 16
#define INV_SQRT_H 0.04419417382415922f

// ---- ws float offsets. [0, ZERO_N) zeroed each launch (atomic accumulators).
#define WKOT_OFF 0          // wkoT[512][16]          8192
#define C_OFF    8192       // [16]
#define OO_OFF   8208       // [B][O][H]              131072 (atomic, 4 kq partials)
#define ZERO_N   139280
#define OQT_OFF  139280     // oqT[512][16]           8192
#define LG_OFF   147472     // [B*S][16]              524288
#define GP_OFF   671760     // [B][32][16][512]       4194304 (plain per-block G partials)
#define LP_OFF   4866064    // [B][32][16]            8192
#define TP_OFF   4874256    // [B][32][16]            8192
#define WVT_OFF  4882448    // [K][H]                 262144  (end 5144592 floats = 20.6 MB)

// ---------------- K1: oq[o,h] = sum_s ops[s,o]*Wq[h,s] + bq[h]
__global__ __launch_bounds__(256) void k_oq(const float* __restrict__ Wq,
                                            const float* __restrict__ bq,
                                            const float* __restrict__ ops,
                                            float* __restrict__ ws,
                                            float* __restrict__ oq_out) {
  const int h = blockIdx.x;
  const int t = threadIdx.x;
  float4 acc[4];
  #pragma unroll
  for (int m = 0; m < 4; ++m) acc[m] = make_float4(0.f, 0.f, 0.f, 0.f);
  for (int s = t; s < SS; s += 256) {
    float wq = Wq[(size_t)h * SS + s];
    const float4* op4 = reinterpret_cast<const float4*>(ops + (size_t)s * ON);
    #pragma unroll
    for (int m = 0; m < 4; ++m) {
      float4 v = op4[m];
      acc[m].x += wq * v.x; acc[m].y += wq * v.y;
      acc[m].z += wq * v.z; acc[m].w += wq * v.w;
    }
  }
  __shared__ float red[256][ON];
  #pragma unroll
  for (int m = 0; m < 4; ++m) {
    red[t][4*m+0] = acc[m].x; red[t][4*m+1] = acc[m].y;
    red[t][4*m+2] = acc[m].z; red[t][4*m+3] = acc[m].w;
  }
  __syncthreads();
  for (int st = 128; st > 0; st >>= 1) {
    if (t < st) {
      #pragma unroll
      for (int o = 0; o < ON; ++o) red[t][o] += red[t + st][o];
    }
    __syncthreads();
  }
  if (t < ON) {
    float v = red[0][t] + bq[h];
    oq_out[(size_t)t * HH + h] = v;          // output 1: operator_queries [O,H]
    ws[OQT_OFF + (size_t)h * ON + t] = v;    // oqT[h][o]
  }
}

// ---------------- K2: wkoT[k][o] = sum_h oq[o,h]*Wk[h,k]; c[o] = sum_h bk[h]*oq[o,h]
__global__ __launch_bounds__(256) void k_wko(const float* __restrict__ Wk,
                                             const float* __restrict__ bk,
                                             float* __restrict__ ws) {
  const int o = blockIdx.x;   // 16
  const int hc = blockIdx.y;  // 8 chunks of 64 h
  const int t = threadIdx.x;
  const float* __restrict__ oqT = ws + OQT_OFF;
  const int h0 = hc * 64;
  float acc0 = 0.f, acc1 = 0.f;
  for (int h = h0; h < h0 + 64; ++h) {
    float q = oqT[(size_t)h * ON + o];
    acc0 += q * Wk[(size_t)h * HH + t];
    acc1 += q * Wk[(size_t)h * HH + t + 256];
  }
  unsafeAtomicAdd(&ws[WKOT_OFF + (size_t)t * ON + o], acc0);
  unsafeAtomicAdd(&ws[WKOT_OFF + (size_t)(t + 256) * ON + o], acc1);
  if (t == 0) {
    float cp = 0.f;
    for (int h = h0; h < h0 + 64; ++h) cp += bk[h] * oqT[(size_t)h * ON + o];
    unsafeAtomicAdd(&ws[C_OFF + o], cp);
  }
}

// ---------------- K3pre: WvT[k][h] = Wv[h][k]
__global__ __launch_bounds__(256) void k_wvt(const float* __restrict__ Wv,
                                             float* __restrict__ ws) {
  __shared__ float tile[32][33];
  const int tx = threadIdx.x, ty = threadIdx.y;
  const int x0 = blockIdx.x * 32, y0 = blockIdx.y * 32;
  #pragma unroll
  for (int j = 0; j < 4; ++j)
    tile[ty + 8 * j][tx] = Wv[(size_t)(y0 + ty + 8 * j) * HH + x0 + tx];
  __syncthreads();
  float* WvT = ws + WVT_OFF;
  #pragma unroll
  for (int j = 0; j < 4; ++j)
    WvT[(size_t)(x0 + ty + 8 * j) * HH + y0 + tx] = tile[tx][ty + 8 * j];
}

// ---------------- K4 (fused): logits + L/t~ partials + G~ partials.
// grid (16 b, 32 sc); 512 threads = 8 waves; 64 rows/block; 2 blocks/CU.
// NO device atomics: per-block plain writes to GP/LP/TP slots.
__global__ __launch_bounds__(512, 4) void k_main(const float* __restrict__ x,
                                                 const float* __restrict__ ops,
                                                 float* __restrict__ ws) {
  const int b = blockIdx.x, sc = blockIdx.y, t = threadIdx.x;
  const int sbase = sc * 64;
  const size_t xbase = ((size_t)b * SS + sbase) * HH;

  __shared__ float red[2][64][20];   // [k-half][row][o] (+pad)
  __shared__ float elb[64][ON];      // exp(logit)
  __shared__ float elo[64][ON];      // exp(logit)*ops[s,o]

  const int w = t >> 6, lane = t & 63;

  // ---- phase A: wave = (kh = k-half, rh = row-group); lane = (row-in-group, o-quad)
  {
    const int kh = w & 1, rh = w >> 1;
    const int rg = lane >> 2, oq = lane & 3;
    const int row = rh * 16 + rg;
    const float* __restrict__ xrow = x + xbase + (size_t)row * HH + kh * 256;
    const float4* __restrict__ wkoT4 = reinterpret_cast<const float4*>(ws + WKOT_OFF);
    const int kb = kh * 256;
    float acc0 = 0.f, acc1 = 0.f, acc2 = 0.f, acc3 = 0.f;
    #pragma unroll 8
    for (int kk = 0; kk < 256; kk += 4) {
      float4 xv = *reinterpret_cast<const float4*>(xrow + kk);
      float4 w0 = wkoT4[(kb + kk + 0) * 4 + oq];
      float4 w1 = wkoT4[(kb + kk + 1) * 4 + oq];
      float4 w2 = wkoT4[(kb + kk + 2) * 4 + oq];
      float4 w3 = wkoT4[(kb + kk + 3) * 4 + oq];
      acc0 += xv.x * w0.x + xv.y * w1.x + xv.z * w2.x + xv.w * w3.x;
      acc1 += xv.x * w0.y + xv.y * w1.y + xv.z * w2.y + xv.w * w3.y;
      acc2 += xv.x * w0.z + xv.y * w1.z + xv.z * w2.z + xv.w * w3.z;
      acc3 += xv.x * w0.w + xv.y * w1.w + xv.z * w2.w + xv.w * w3.w;
    }
    *reinterpret_cast<float4*>(&red[kh][row][oq * 4]) =
        make_float4(acc0, acc1, acc2, acc3);
  }
  __syncthreads();

  // ---- finalize logits: 1024 (r,o) pairs / 512 threads = 2 each
  #pragma unroll
  for (int p = 0; p < 2; ++p) {
    const int e = t + p * 512;
    const int r = e >> 4, o = e & 15;
    float sv = red[0][r][o] + red[1][r][o] + ws[C_OFF + o];
    float lg = sv * INV_SQRT_H;
    ws[LG_OFF + ((size_t)b * SS + sbase + r) * ON + o] = lg;
    // exp without max-subtract: |logit| <~ 3 for this data, fp32-safe
    float ev = __expf(lg);
    elb[r][o] = ev;
    elo[r][o] = ev * ops[(size_t)(sbase + r) * ON + o];
  }
  __syncthreads();

  // ---- L and t~ per-block partials (plain writes, no contention)
  if (t < ON) {
    float sl = 0.f, st2 = 0.f;
    #pragma unroll
    for (int r = 0; r < 64; ++r) { sl += elb[r][t]; st2 += elo[r][t]; }
    ws[LP_OFF + (size_t)(b * 32 + sc) * ON + t] = sl;
    ws[TP_OFF + (size_t)(b * 32 + sc) * ON + t] = st2;
  }

  // ---- phase B: GP[b][sc][o][k] = sum_s elo[s][o]*x[s][k]
  // wave = (o-quad = w>>1, k-half = w&1); lane = k-float4 within half. x is L1/L2-hot.
  {
    const int oq4 = w >> 1, khB = w & 1;
    const int k4 = khB * 64 + lane;        // float4 index within the row
    const float4* __restrict__ x4 = reinterpret_cast<const float4*>(x + xbase);
    float4 a0 = make_float4(0,0,0,0), a1 = a0, a2 = a0, a3 = a0;
    #pragma unroll 4
    for (int s = 0; s < 64; ++s) {
      float4 xv = x4[(size_t)s * 128 + k4];
      float4 ev = *reinterpret_cast<const float4*>(&elo[s][oq4 * 4]);
      a0.x += ev.x * xv.x; a0.y += ev.x * xv.y; a0.z += ev.x * xv.z; a0.w += ev.x * xv.w;
      a1.x += ev.y * xv.x; a1.y += ev.y * xv.y; a1.z += ev.y * xv.z; a1.w += ev.y * xv.w;
      a2.x += ev.z * xv.x; a2.y += ev.z * xv.y; a2.z += ev.z * xv.z; a2.w += ev.z * xv.w;
      a3.x += ev.w * xv.x; a3.y += ev.w * xv.y; a3.z += ev.w * xv.z; a3.w += ev.w * xv.w;
    }
    float4* gp4 = reinterpret_cast<float4*>(ws + GP_OFF);
    const size_t gbase = ((size_t)(b * 32 + sc) * 16 + oq4 * 4) * 128 + k4;
    gp4[gbase          ] = a0;
    gp4[gbase + 128    ] = a1;
    gp4[gbase + 256    ] = a2;
    gp4[gbase + 384    ] = a3;
  }
}

// ---------------- K5: reduce GP over sc, then OO = G/L @ WvT + bv*t~/L.
// grid (16 b, 4 o-quad, 4 k-quarter), 256 thr.
__global__ __launch_bounds__(256) void k_oo(const float* __restrict__ bv,
                                            float* __restrict__ ws) {
  const int b = blockIdx.x, oqi = blockIdx.y, kq = blockIdx.z, t = threadIdx.x;
  const int o0 = oqi * 4, k0 = kq * 128;
  __shared__ float Gs[4][128];
  __shared__ float invLs[4], tts[4];
  const int w = t >> 6, lane = t & 63;
  // L/TT reduction: wave w handles o0+w, lanes = sc (32 of them)
  float lp = 0.f, tp = 0.f;
  if (lane < 32) {
    lp = ws[LP_OFF + (size_t)(b * 32 + lane) * ON + o0 + w];
    tp = ws[TP_OFF + (size_t)(b * 32 + lane) * ON + o0 + w];
  }
  #pragma unroll
  for (int off = 16; off > 0; off >>= 1) {
    lp += __shfl_down(lp, off);
    tp += __shfl_down(tp, off);
  }
  if (lane == 0) { float inv = 1.f / lp; invLs[w] = inv; tts[w] = tp * inv; }
  __syncthreads();
  // G reduction over the 32 sc partials
  #pragma unroll
  for (int p = 0; p < 2; ++p) {
    const int e = t + p * 256;
    const int ol = e >> 7, kl = e & 127;
    float s = 0.f;
    #pragma unroll 8
    for (int sc = 0; sc < 32; ++sc)
      s += ws[GP_OFF + ((size_t)(b * 32 + sc) * 16 + o0 + ol) * 512 + k0 + kl];
    Gs[ol][kl] = s * invLs[ol];
  }
  __syncthreads();
  const float* __restrict__ WvT = ws + WVT_OFF;
  float acc[4][2];
  #pragma unroll
  for (int o = 0; o < 4; ++o) { acc[o][0] = 0.f; acc[o][1] = 0.f; }
  for (int k = 0; k < 128; ++k) {
    const float w0 = WvT[(size_t)(k0 + k) * HH + t];
    const float w1 = WvT[(size_t)(k0 + k) * HH + t + 256];
    #pragma unroll
    for (int o = 0; o < 4; ++o) {
      const float g = Gs[o][k];
      acc[o][0] += g * w0; acc[o][1] += g * w1;
    }
  }
  float* OOp = ws + OO_OFF + ((size_t)b * ON + o0) * HH;
  #pragma unroll
  for (int o = 0; o < 4; ++o) {
    float add0 = acc[o][0], add1 = acc[o][1];
    if (kq == 0) { add0 += bv[t] * tts[o]; add1 += bv[t + 256] * tts[o]; }
    unsafeAtomicAdd(&OOp[(size_t)o * HH + t], add0);
    unsafeAtomicAdd(&OOp[(size_t)o * HH + t + 256], add1);
  }
}

// ---------------- K6: out[row,h] = sum_o softmax_o(lg[row,:])[o] * OO[b,o,h]
// grid (16 b, 32 sc): 64 rows/block, 2 blocks/CU.
__global__ __launch_bounds__(256) void k_out(float* __restrict__ ws,
                                             float* __restrict__ out) {
  const int b = blockIdx.x, sc = blockIdx.y, t = threadIdx.x;
  const int rbase = b * SS + sc * 64;
  __shared__ float OOs[ON * HH];     // 32 KB
  __shared__ float wl[64 * ON];      // 4 KB
  const float4* OO4 = reinterpret_cast<const float4*>(ws + OO_OFF + (size_t)(b * ON) * HH);
  float4* OOs4 = reinterpret_cast<float4*>(OOs);
  #pragma unroll
  for (int j = 0; j < 8; ++j) OOs4[t + 256 * j] = OO4[t + 256 * j];
  if (t < 64) {
    const float4* lg4 = reinterpret_cast<const float4*>(ws + LG_OFF + (size_t)(rbase + t) * ON);
    float l[ON];
    float4 p0 = lg4[0], p1 = lg4[1], p2 = lg4[2], p3 = lg4[3];
    l[0]=p0.x; l[1]=p0.y; l[2]=p0.z; l[3]=p0.w;
    l[4]=p1.x; l[5]=p1.y; l[6]=p1.z; l[7]=p1.w;
    l[8]=p2.x; l[9]=p2.y; l[10]=p2.z; l[11]=p2.w;
    l[12]=p3.x; l[13]=p3.y; l[14]=p3.z; l[15]=p3.w;
    float m = l[0];
    #pragma unroll
    for (int o = 1; o < ON; ++o) m = fmaxf(m, l[o]);
    float sum = 0.f;
    #pragma unroll
    for (int o = 0; o < ON; ++o) { l[o] = __expf(l[o] - m); sum += l[o]; }
    float inv = 1.f / sum;
    #pragma unroll
    for (int o = 0; o < ON; ++o) wl[t * ON + o] = l[o] * inv;
  }
  __syncthreads();
  const int rsub = t >> 7, hq = t & 127;
  float oo[ON][4];
  #pragma unroll
  for (int o = 0; o < ON; ++o)
    #pragma unroll
    for (int j = 0; j < 4; ++j) oo[o][j] = OOs[o * HH + hq + 128 * j];
  const float4* wl4 = reinterpret_cast<const float4*>(wl);
  for (int i = 0; i < 32; ++i) {
    const int r = rsub * 32 + i;
    float4 w0 = wl4[r * 4 + 0], w1 = wl4[r * 4 + 1], w2 = wl4[r * 4 + 2], w3 = wl4[r * 4 + 3];
    float w[ON];
    w[0]=w0.x; w[1]=w0.y; w[2]=w0.z; w[3]=w0.w;
    w[4]=w1.x; w[5]=w1.y; w[6]=w1.z; w[7]=w1.w;
    w[8]=w2.x; w[9]=w2.y; w[10]=w2.z; w[11]=w2.w;
    w[12]=w3.x; w[13]=w3.y; w[14]=w3.z; w[15]=w3.w;
    float* orow = out + (size_t)(rbase + r) * HH + hq;
    #pragma unroll
    for (int j = 0; j < 4; ++j) {
      float v = 0.f;
      #pragma unroll
      for (int o = 0; o < ON; ++o) v += w[o] * oo[o][j];
      orow[128 * j] = v;
    }
  }
}

extern "C" void kernel_launch(void* const* d_in, const int* in_sizes, int n_in,
                              void* d_out, int out_size, void* d_ws, size_t ws_size,
                              hipStream_t stream) {
  const float* x   = (const float*)d_in[0];
  const float* Wv  = (const float*)d_in[1];
  const float* bv  = (const float*)d_in[2];
  const float* Wk  = (const float*)d_in[3];
  const float* bk  = (const float*)d_in[4];
  const float* Wq  = (const float*)d_in[5];
  const float* bq  = (const float*)d_in[6];
  const float* ops = (const float*)d_in[7];
  float* out = (float*)d_out;
  float* ws  = (float*)d_ws;
  float* oq_out = out + (size_t)BB * SS * HH;

  // zero only the atomic accumulators (wkoT, c, OO)
  hipMemsetAsync(ws, 0, (size_t)ZERO_N * sizeof(float), stream);

  k_wvt<<<dim3(16, 16), dim3(32, 8), 0, stream>>>(Wv, ws);
  k_oq<<<512, 256, 0, stream>>>(Wq, bq, ops, ws, oq_out);
  k_wko<<<dim3(16, 8), 256, 0, stream>>>(Wk, bk, ws);
  k_main<<<dim3(16, 32), 512, 0, stream>>>(x, ops, ws);
  k_oo<<<dim3(16, 4, 4), 256, 0, stream>>>(bv, ws);
  k_out<<<dim3(16, 32), 256, 0, stream>>>(ws, out);
}